// Round 7
// baseline (235.871 us; speedup 1.0000x reference)
//
#include <hip/hip_runtime.h>

// LiftSplatShoot dims
#define B_   8
#define N_   6
#define D_   41
#define FH_  8
#define FW_  22
#define C_   64
#define NPRIME (B_*N_*D_*FH_*FW_)   // 346368 = 1353 * 256 exactly
#define NBLK_PTS 1353
#define NX0  200
#define NX1  200
#define G1Q  4                      // g1 quarters of 50
#define NB2  (B_ * NX0 * G1Q)       // 6400 buckets (b, g0, g1/50)
#define OUTSZ (B_*C_*NX0*NX1)       // 20,480,000 floats
#define CAP  256                    // max entries per gather task
#define DIRECT_N 48                 // small-task direct-atomic path (no LDS)
#define MAXTASKS 8192
#define GATHER_BLOCKS 1024

// ---------------- numpy-faithful fp32 3x3 inverse (LAPACK sgetrf+sgetri) ----
__device__ void lapack_inv3_f32(const float Ain[9], float Aout[9]) {
    #pragma clang fp contract(off)
    float a[9]; // column-major
    for (int r = 0; r < 3; ++r)
        for (int c = 0; c < 3; ++c)
            a[c*3 + r] = Ain[r*3 + c];
    int ipiv[3];
    for (int j = 0; j < 3; ++j) {
        int p = j;
        float amax = fabsf(a[j*3 + j]);
        for (int i = j + 1; i < 3; ++i) {
            float v = fabsf(a[j*3 + i]);
            if (v > amax) { amax = v; p = i; }
        }
        ipiv[j] = p;
        if (p != j)
            for (int c = 0; c < 3; ++c) { float t = a[c*3+j]; a[c*3+j] = a[c*3+p]; a[c*3+p] = t; }
        float d = 1.0f / a[j*3 + j];
        for (int i = j + 1; i < 3; ++i) a[j*3 + i] = a[j*3 + i] * d;
        for (int jj = j + 1; jj < 3; ++jj) {
            float temp = -a[jj*3 + j];
            for (int ii = j + 1; ii < 3; ++ii)
                a[jj*3 + ii] = a[jj*3 + ii] + a[j*3 + ii] * temp;
        }
    }
    for (int j = 0; j < 3; ++j) {
        float ajj_inv = 1.0f / a[j*3 + j];
        a[j*3 + j] = ajj_inv;
        float AJJ = -ajj_inv;
        for (int jj = 0; jj < j; ++jj) {
            float temp = a[j*3 + jj];
            for (int i = 0; i < jj; ++i)
                a[j*3 + i] = a[j*3 + i] + temp * a[jj*3 + i];
            a[j*3 + jj] = a[j*3 + jj] * a[jj*3 + jj];
        }
        for (int i = 0; i < j; ++i) a[j*3 + i] = a[j*3 + i] * AJJ;
    }
    float work[3];
    for (int j = 2; j >= 0; --j) {
        for (int i = j + 1; i < 3; ++i) { work[i] = a[j*3 + i]; a[j*3 + i] = 0.0f; }
        for (int jj = j + 1; jj < 3; ++jj) {
            float temp = -work[jj];
            for (int i = 0; i < 3; ++i)
                a[j*3 + i] = a[j*3 + i] + temp * a[jj*3 + i];
        }
    }
    for (int j = 2; j >= 0; --j) {
        int p = ipiv[j];
        if (p != j)
            for (int i = 0; i < 3; ++i) { float t = a[j*3+i]; a[j*3+i] = a[p*3+i]; a[p*3+i] = t; }
    }
    for (int r = 0; r < 3; ++r)
        for (int c = 0; c < 3; ++c)
            Aout[r*3 + c] = a[c*3 + r];
}

// prep (threads 0..47) + zero bucket counters.
__global__ void prep_kernel(const float* __restrict__ rots,
                            const float* __restrict__ trans,
                            const float* __restrict__ intrins,
                            const float* __restrict__ post_rots,
                            const float* __restrict__ post_trans,
                            float* __restrict__ mats,
                            int* __restrict__ counts) {
    #pragma clang fp contract(off)
    int t = threadIdx.x;
    for (int i = t; i < NB2; i += 256) counts[i] = 0;
    if (t >= B_ * N_) return;
    float pr[9], ipr[9], K[9], iK[9];
    for (int i = 0; i < 9; ++i) { pr[i] = post_rots[t*9 + i]; K[i] = intrins[t*9 + i]; }
    lapack_inv3_f32(pr, ipr);
    lapack_inv3_f32(K, iK);
    float* m = mats + t * 24;
    for (int i = 0; i < 9; ++i) m[i] = ipr[i];
    for (int i = 0; i < 3; ++i)
        for (int k = 0; k < 3; ++k) {
            float s = rots[t*9 + i*3 + 0] * iK[0*3 + k];
            s = s + rots[t*9 + i*3 + 1] * iK[1*3 + k];
            s = s + rots[t*9 + i*3 + 2] * iK[2*3 + k];
            m[9 + i*3 + k] = s;
        }
    for (int i = 0; i < 3; ++i) {
        m[18 + i] = post_trans[t*3 + i];
        m[21 + i] = trans[t*3 + i];
    }
}

// One thread per point (grid exact): fp32 numpy-faithful geometry ->
// pcode=(bk<<6)|g1r; block-local LDS histogram -> hierarchical flush.
// Also grid-stride zeroes the output (out poisoned each launch).
__global__ void __launch_bounds__(256) geom_kernel(
        const float* __restrict__ mats,
        unsigned int* __restrict__ pcode,
        int* __restrict__ counts,
        float4* __restrict__ out4) {
    #pragma clang fp contract(off)
    __shared__ unsigned int hist[NB2];   // 25.6 KB
    int t = threadIdx.x;
    int p = blockIdx.x * 256 + t;
    for (int i = t; i < NB2; i += 256) hist[i] = 0u;
    __syncthreads();

    int w  = p % FW_;
    int h  = (p / FW_) % FH_;
    int d  = (p / (FW_ * FH_)) % D_;
    int bn = p / (FW_ * FH_ * D_);
    int b  = bn / N_;

    const float* m = mats + bn * 24;

    float xs = (w == FW_ - 1) ? 351.0f : (float)((double)w * (351.0 / 21.0));
    float ys = (h == FH_ - 1) ? 127.0f : (float)((double)h * (127.0 / 7.0));
    float ds = 4.0f + (float)d;

    float px = xs - m[18], py = ys - m[19], pz = ds - m[20];
    float qx = m[0]*px;  qx = qx + m[1]*py;  qx = qx + m[2]*pz;
    float qy = m[3]*px;  qy = qy + m[4]*py;  qy = qy + m[5]*pz;
    float qz = m[6]*px;  qz = qz + m[7]*py;  qz = qz + m[8]*pz;

    float ux = qx * qz, uy = qy * qz, uz = qz;

    float gx = m[9]*ux;   gx = gx + m[10]*uy;  gx = gx + m[11]*uz;  gx = gx + m[21];
    float gy = m[12]*ux;  gy = gy + m[13]*uy;  gy = gy + m[14]*uz;  gy = gy + m[22];
    float gz = m[15]*ux;  gz = gz + m[16]*uy;  gz = gz + m[17]*uz;  gz = gz + m[23];

    float cx = (gx - (-50.0f)) / 0.5f;
    float cy = (gy - (-50.0f)) / 0.5f;
    float cz = (gz - (-10.0f)) / 20.0f;
    int g0 = (int)cx;
    int g1 = (int)cy;
    int g2 = (int)cz;

    bool kept = (g0 >= 0) && (g0 < NX0) && (g1 >= 0) && (g1 < NX1) && (g2 == 0);
    if (kept) {
        int g1q = g1 / 50;
        int g1r = g1 - g1q * 50;
        int bk  = (b * NX0 + g0) * G1Q + g1q;
        pcode[p] = ((unsigned int)bk << 6) | (unsigned int)g1r;
        atomicAdd(&hist[bk], 1u);
    } else {
        pcode[p] = 0xFFFFFFFFu;
    }
    __syncthreads();
    for (int i = t; i < NB2; i += 256) {
        unsigned int hv = hist[i];
        if (hv) atomicAdd(&counts[i], (int)hv);
    }

    // zero the output grid (float4 streaming)
    const int TOT4 = OUTSZ / 4;
    float4 z4 = make_float4(0.f, 0.f, 0.f, 0.f);
    for (int i = p; i < TOT4; i += NPRIME) out4[i] = z4;
}

// Single-block: exclusive scan over 6400 counts -> offsets, cursor; emit
// size-capped tasks (no global atomics): bit31=sole, bits[12:25)=bucket,
// bits[0:12)=chunk. Also zero-inits the gather work cursor.
__global__ void scan_kernel(const int* __restrict__ counts,
                            int* __restrict__ offsets,
                            int* __restrict__ cursor,
                            unsigned int* __restrict__ tasks,
                            int* __restrict__ task_count,
                            int* __restrict__ wcursor) {
    __shared__ int ts[256];
    __shared__ int tbase_s[256];
    int t = threadIdx.x;
    const int PER = NB2 / 256; // 25
    int base = t * PER;
    int mysum = 0, mytasks = 0;
    for (int j = 0; j < PER; ++j) {
        int c = counts[base + j];
        mysum += c;
        if (c > 0) mytasks += (c + CAP - 1) / CAP;
    }
    ts[t] = mysum;
    tbase_s[t] = mytasks;
    __syncthreads();
    for (int off = 1; off < 256; off <<= 1) {
        int v  = (t >= off) ? ts[t - off] : 0;
        int tv = (t >= off) ? tbase_s[t - off] : 0;
        __syncthreads();
        ts[t] += v;
        tbase_s[t] += tv;
        __syncthreads();
    }
    int run  = (t > 0) ? ts[t - 1] : 0;       // exclusive entry base
    int tpos = (t > 0) ? tbase_s[t - 1] : 0;  // exclusive task base
    for (int j = 0; j < PER; ++j) {
        int c = counts[base + j];
        offsets[base + j] = run;
        cursor[base + j]  = run;
        run += c;
        if (c > 0) {
            int nch = (c + CAP - 1) / CAP;
            unsigned int sole = (nch == 1) ? (1u << 31) : 0u;
            for (int k = 0; k < nch; ++k)
                tasks[tpos++] = sole | ((unsigned int)(base + j) << 12) | (unsigned int)k;
        }
    }
    if (t == 255) {
        offsets[NB2] = run;
        task_count[0] = tbase_s[255];
        wcursor[0] = 0;
    }
}

// Compact kept points: block-aggregated reservation (one global atomic per
// block x touched-bucket); cnt[] is reused to hold the global base (25.6 KB).
__global__ void __launch_bounds__(256) place_kernel(
        const unsigned int* __restrict__ pcode,
        int* __restrict__ cursor,
        unsigned int* __restrict__ entries) {
    __shared__ int cnt[NB2];   // 25.6 KB (counts, then global bases)
    int t = threadIdx.x;
    int p = blockIdx.x * 256 + t;
    for (int i = t; i < NB2; i += 256) cnt[i] = 0;
    __syncthreads();
    unsigned int code = pcode[p];
    bool kept = (code != 0xFFFFFFFFu);
    int bk = (int)(code >> 6);
    int lr = 0;
    if (kept) lr = atomicAdd(&cnt[bk], 1);
    __syncthreads();
    for (int i = t; i < NB2; i += 256) {
        int c = cnt[i];
        if (c) cnt[i] = atomicAdd(&cursor[i], c);   // overwrite with global base
    }
    __syncthreads();
    if (kept)
        entries[cnt[bk] + lr] = ((code & 63u) << 19) | (unsigned int)p;
}

// Persistent-block gather with dynamic work-stealing over size-capped tasks.
// Out is pre-zeroed: sole tasks store nonzero cells, multi-chunk tasks
// atomic-flush, tiny tasks (n<=DIRECT_N) bypass LDS with direct atomics.
#define LDS_STRIDE 51
__global__ void __launch_bounds__(256) gather_kernel(
        const float* __restrict__ x_feats,
        const unsigned int* __restrict__ entries,
        const int* __restrict__ offsets,
        const unsigned int* __restrict__ tasks,
        const int* __restrict__ task_count,
        int* __restrict__ wcursor,
        float* __restrict__ out) {
    __shared__ float acc[C_ * LDS_STRIDE]; // 13056 B
    __shared__ int sh_task;
    int ntask = task_count[0];
    int t = threadIdx.x, wave = t >> 6, lane = t & 63;

    for (;;) {
        if (t == 0) sh_task = atomicAdd(wcursor, 1);
        __syncthreads();
        int tid = sh_task;
        __syncthreads();              // protect sh_task before next overwrite
        if (tid >= ntask) return;

        unsigned int task = tasks[tid];
        int sole = (int)(task >> 31);
        int bk   = (int)((task >> 12) & 0x1FFFu);
        int ch   = (int)(task & 0xFFFu);
        int s = offsets[bk] + ch * CAP;
        int e = offsets[bk + 1];
        if (e > s + CAP) e = s + CAP;
        int n = e - s;

        int b   = bk / (NX0 * G1Q);
        int rem = bk % (NX0 * G1Q);
        int g0  = rem / G1Q, g1q = rem % G1Q;
        size_t obase = (size_t)b * (C_ * NX0 * NX1) + (size_t)g0 * NX1 + g1q * 50;

        if (n <= DIRECT_N) {
            for (int i = wave; i < n; i += 4) {
                unsigned int v = entries[s + i];
                float f = x_feats[(size_t)(v & 0x7FFFFu) * C_ + lane];
                unsafeAtomicAdd(&out[obase + (size_t)lane * (NX0 * NX1) + (int)(v >> 19)], f);
            }
            continue;
        }

        for (int i = t; i < C_ * LDS_STRIDE; i += 256) acc[i] = 0.0f;
        __syncthreads();

        int i = wave * 4;
        for (; i + 4 <= n; i += 16) {
            unsigned int v0 = entries[s + i],     v1 = entries[s + i + 1];
            unsigned int v2 = entries[s + i + 2], v3 = entries[s + i + 3];
            float f0 = x_feats[(size_t)(v0 & 0x7FFFFu) * C_ + lane];
            float f1 = x_feats[(size_t)(v1 & 0x7FFFFu) * C_ + lane];
            float f2 = x_feats[(size_t)(v2 & 0x7FFFFu) * C_ + lane];
            float f3 = x_feats[(size_t)(v3 & 0x7FFFFu) * C_ + lane];
            atomicAdd(&acc[lane * LDS_STRIDE + (int)(v0 >> 19)], f0);
            atomicAdd(&acc[lane * LDS_STRIDE + (int)(v1 >> 19)], f1);
            atomicAdd(&acc[lane * LDS_STRIDE + (int)(v2 >> 19)], f2);
            atomicAdd(&acc[lane * LDS_STRIDE + (int)(v3 >> 19)], f3);
        }
        for (; i < n; ++i) {
            unsigned int v = entries[s + i];
            float f = x_feats[(size_t)(v & 0x7FFFFu) * C_ + lane];
            atomicAdd(&acc[lane * LDS_STRIDE + (int)(v >> 19)], f);
        }
        __syncthreads();

        for (int k = t; k < C_ * 50; k += 256) {
            int c = k / 50, r = k - c * 50;
            float val = acc[c * LDS_STRIDE + r];
            if (val != 0.0f) {
                float* dst = &out[obase + (size_t)c * (NX0 * NX1) + r];
                if (sole) *dst = val;
                else unsafeAtomicAdd(dst, val);
            }
        }
        __syncthreads();
    }
}

extern "C" void kernel_launch(void* const* d_in, const int* in_sizes, int n_in,
                              void* d_out, int out_size, void* d_ws, size_t ws_size,
                              hipStream_t stream) {
    const float* x_feats    = (const float*)d_in[0];
    const float* rots       = (const float*)d_in[1];
    const float* trans      = (const float*)d_in[2];
    const float* intrins    = (const float*)d_in[3];
    const float* post_rots  = (const float*)d_in[4];
    const float* post_trans = (const float*)d_in[5];
    float* out = (float*)d_out;

    // ws layout (~2.9 MB)
    char* w = (char*)d_ws;
    float*        mats       = (float*)w;         w += 48 * 24 * sizeof(float);
    int*          counts     = (int*)w;           w += NB2 * sizeof(int);
    int*          offsets    = (int*)w;           w += (NB2 + 1) * sizeof(int);
    int*          cursor     = (int*)w;           w += NB2 * sizeof(int);
    int*          task_count = (int*)w;           w += 4 * sizeof(int);
    int*          wcursor    = (int*)w;           w += 4 * sizeof(int);
    unsigned int* tasks      = (unsigned int*)w;  w += MAXTASKS * sizeof(unsigned int);
    unsigned int* pcode      = (unsigned int*)w;  w += NPRIME * sizeof(unsigned int);
    unsigned int* entries    = (unsigned int*)w;  w += NPRIME * sizeof(unsigned int);

    prep_kernel<<<1, 256, 0, stream>>>(rots, trans, intrins, post_rots, post_trans,
                                       mats, counts);
    geom_kernel<<<NBLK_PTS, 256, 0, stream>>>(mats, pcode, counts, (float4*)out);
    scan_kernel<<<1, 256, 0, stream>>>(counts, offsets, cursor, tasks,
                                       task_count, wcursor);
    place_kernel<<<NBLK_PTS, 256, 0, stream>>>(pcode, cursor, entries);
    gather_kernel<<<GATHER_BLOCKS, 256, 0, stream>>>(x_feats, entries, offsets,
                                                     tasks, task_count, wcursor, out);
}

// Round 8
// 209.167 us; speedup vs baseline: 1.1277x; 1.1277x over previous
//
#include <hip/hip_runtime.h>

// LiftSplatShoot dims
#define B_   8
#define N_   6
#define D_   41
#define FH_  8
#define FW_  22
#define C_   64
#define NPRIME (B_*N_*D_*FH_*FW_)   // 346368 = 1353 * 256 exactly
#define NBLK_PTS 1353
#define NX0  200
#define NX1  200
#define G1Q  4                      // g1 quarters of 50
#define NB2  (B_ * NX0 * G1Q)       // 6400 buckets (b, g0, g1/50)
#define OUTSZ (B_*C_*NX0*NX1)       // 20,480,000 floats
#define CAP  128                    // max entries per gather task (short chains)
#define DIRECT_N 16                 // small-task direct-atomic path (no LDS)
#define MAXTASKS 16384              // >= 346368/128 + 6400 worst case
#define GATHER_BLOCKS 1024          // exactly one co-resident wave of blocks

// ---------------- numpy-faithful fp32 3x3 inverse (LAPACK sgetrf+sgetri) ----
__device__ void lapack_inv3_f32(const float Ain[9], float Aout[9]) {
    #pragma clang fp contract(off)
    float a[9]; // column-major
    for (int r = 0; r < 3; ++r)
        for (int c = 0; c < 3; ++c)
            a[c*3 + r] = Ain[r*3 + c];
    int ipiv[3];
    for (int j = 0; j < 3; ++j) {
        int p = j;
        float amax = fabsf(a[j*3 + j]);
        for (int i = j + 1; i < 3; ++i) {
            float v = fabsf(a[j*3 + i]);
            if (v > amax) { amax = v; p = i; }
        }
        ipiv[j] = p;
        if (p != j)
            for (int c = 0; c < 3; ++c) { float t = a[c*3+j]; a[c*3+j] = a[c*3+p]; a[c*3+p] = t; }
        float d = 1.0f / a[j*3 + j];
        for (int i = j + 1; i < 3; ++i) a[j*3 + i] = a[j*3 + i] * d;
        for (int jj = j + 1; jj < 3; ++jj) {
            float temp = -a[jj*3 + j];
            for (int ii = j + 1; ii < 3; ++ii)
                a[jj*3 + ii] = a[jj*3 + ii] + a[j*3 + ii] * temp;
        }
    }
    for (int j = 0; j < 3; ++j) {
        float ajj_inv = 1.0f / a[j*3 + j];
        a[j*3 + j] = ajj_inv;
        float AJJ = -ajj_inv;
        for (int jj = 0; jj < j; ++jj) {
            float temp = a[j*3 + jj];
            for (int i = 0; i < jj; ++i)
                a[j*3 + i] = a[j*3 + i] + temp * a[jj*3 + i];
            a[j*3 + jj] = a[j*3 + jj] * a[jj*3 + jj];
        }
        for (int i = 0; i < j; ++i) a[j*3 + i] = a[j*3 + i] * AJJ;
    }
    float work[3];
    for (int j = 2; j >= 0; --j) {
        for (int i = j + 1; i < 3; ++i) { work[i] = a[j*3 + i]; a[j*3 + i] = 0.0f; }
        for (int jj = j + 1; jj < 3; ++jj) {
            float temp = -work[jj];
            for (int i = 0; i < 3; ++i)
                a[j*3 + i] = a[j*3 + i] + temp * a[jj*3 + i];
        }
    }
    for (int j = 2; j >= 0; --j) {
        int p = ipiv[j];
        if (p != j)
            for (int i = 0; i < 3; ++i) { float t = a[j*3+i]; a[j*3+i] = a[p*3+i]; a[p*3+i] = t; }
    }
    for (int r = 0; r < 3; ++r)
        for (int c = 0; c < 3; ++c)
            Aout[r*3 + c] = a[c*3 + r];
}

// prep (threads 0..47) + zero bucket counters.
__global__ void prep_kernel(const float* __restrict__ rots,
                            const float* __restrict__ trans,
                            const float* __restrict__ intrins,
                            const float* __restrict__ post_rots,
                            const float* __restrict__ post_trans,
                            float* __restrict__ mats,
                            int* __restrict__ counts) {
    #pragma clang fp contract(off)
    int t = threadIdx.x;
    for (int i = t; i < NB2; i += 256) counts[i] = 0;
    if (t >= B_ * N_) return;
    float pr[9], ipr[9], K[9], iK[9];
    for (int i = 0; i < 9; ++i) { pr[i] = post_rots[t*9 + i]; K[i] = intrins[t*9 + i]; }
    lapack_inv3_f32(pr, ipr);
    lapack_inv3_f32(K, iK);
    float* m = mats + t * 24;
    for (int i = 0; i < 9; ++i) m[i] = ipr[i];
    for (int i = 0; i < 3; ++i)
        for (int k = 0; k < 3; ++k) {
            float s = rots[t*9 + i*3 + 0] * iK[0*3 + k];
            s = s + rots[t*9 + i*3 + 1] * iK[1*3 + k];
            s = s + rots[t*9 + i*3 + 2] * iK[2*3 + k];
            m[9 + i*3 + k] = s;
        }
    for (int i = 0; i < 3; ++i) {
        m[18 + i] = post_trans[t*3 + i];
        m[21 + i] = trans[t*3 + i];
    }
}

// One thread per point (grid exact): fp32 numpy-faithful geometry ->
// pcode=(bk<<6)|g1r; block-local LDS histogram -> hierarchical flush.
// Also grid-stride zeroes the output (out poisoned each launch).
__global__ void __launch_bounds__(256) geom_kernel(
        const float* __restrict__ mats,
        unsigned int* __restrict__ pcode,
        int* __restrict__ counts,
        float4* __restrict__ out4) {
    #pragma clang fp contract(off)
    __shared__ unsigned int hist[NB2];   // 25.6 KB
    int t = threadIdx.x;
    int p = blockIdx.x * 256 + t;
    for (int i = t; i < NB2; i += 256) hist[i] = 0u;
    __syncthreads();

    int w  = p % FW_;
    int h  = (p / FW_) % FH_;
    int d  = (p / (FW_ * FH_)) % D_;
    int bn = p / (FW_ * FH_ * D_);
    int b  = bn / N_;

    const float* m = mats + bn * 24;

    float xs = (w == FW_ - 1) ? 351.0f : (float)((double)w * (351.0 / 21.0));
    float ys = (h == FH_ - 1) ? 127.0f : (float)((double)h * (127.0 / 7.0));
    float ds = 4.0f + (float)d;

    float px = xs - m[18], py = ys - m[19], pz = ds - m[20];
    float qx = m[0]*px;  qx = qx + m[1]*py;  qx = qx + m[2]*pz;
    float qy = m[3]*px;  qy = qy + m[4]*py;  qy = qy + m[5]*pz;
    float qz = m[6]*px;  qz = qz + m[7]*py;  qz = qz + m[8]*pz;

    float ux = qx * qz, uy = qy * qz, uz = qz;

    float gx = m[9]*ux;   gx = gx + m[10]*uy;  gx = gx + m[11]*uz;  gx = gx + m[21];
    float gy = m[12]*ux;  gy = gy + m[13]*uy;  gy = gy + m[14]*uz;  gy = gy + m[22];
    float gz = m[15]*ux;  gz = gz + m[16]*uy;  gz = gz + m[17]*uz;  gz = gz + m[23];

    float cx = (gx - (-50.0f)) / 0.5f;
    float cy = (gy - (-50.0f)) / 0.5f;
    float cz = (gz - (-10.0f)) / 20.0f;
    int g0 = (int)cx;
    int g1 = (int)cy;
    int g2 = (int)cz;

    bool kept = (g0 >= 0) && (g0 < NX0) && (g1 >= 0) && (g1 < NX1) && (g2 == 0);
    if (kept) {
        int g1q = g1 / 50;
        int g1r = g1 - g1q * 50;
        int bk  = (b * NX0 + g0) * G1Q + g1q;
        pcode[p] = ((unsigned int)bk << 6) | (unsigned int)g1r;
        atomicAdd(&hist[bk], 1u);
    } else {
        pcode[p] = 0xFFFFFFFFu;
    }
    __syncthreads();
    for (int i = t; i < NB2; i += 256) {
        unsigned int hv = hist[i];
        if (hv) atomicAdd(&counts[i], (int)hv);
    }

    // zero the output grid (float4 streaming)
    const int TOT4 = OUTSZ / 4;
    float4 z4 = make_float4(0.f, 0.f, 0.f, 0.f);
    for (int i = p; i < TOT4; i += NPRIME) out4[i] = z4;
}

// Single-block: exclusive scan over 6400 counts -> offsets, cursor; emit
// size-capped tasks (no global atomics): bit31=sole, bits[12:25)=bucket,
// bits[0:12)=chunk.
__global__ void scan_kernel(const int* __restrict__ counts,
                            int* __restrict__ offsets,
                            int* __restrict__ cursor,
                            unsigned int* __restrict__ tasks,
                            int* __restrict__ task_count) {
    __shared__ int ts[256];
    __shared__ int tbase_s[256];
    int t = threadIdx.x;
    const int PER = NB2 / 256; // 25
    int base = t * PER;
    int mysum = 0, mytasks = 0;
    for (int j = 0; j < PER; ++j) {
        int c = counts[base + j];
        mysum += c;
        if (c > 0) mytasks += (c + CAP - 1) / CAP;
    }
    ts[t] = mysum;
    tbase_s[t] = mytasks;
    __syncthreads();
    for (int off = 1; off < 256; off <<= 1) {
        int v  = (t >= off) ? ts[t - off] : 0;
        int tv = (t >= off) ? tbase_s[t - off] : 0;
        __syncthreads();
        ts[t] += v;
        tbase_s[t] += tv;
        __syncthreads();
    }
    int run  = (t > 0) ? ts[t - 1] : 0;       // exclusive entry base
    int tpos = (t > 0) ? tbase_s[t - 1] : 0;  // exclusive task base
    for (int j = 0; j < PER; ++j) {
        int c = counts[base + j];
        offsets[base + j] = run;
        cursor[base + j]  = run;
        run += c;
        if (c > 0) {
            int nch = (c + CAP - 1) / CAP;
            unsigned int sole = (nch == 1) ? (1u << 31) : 0u;
            for (int k = 0; k < nch; ++k)
                tasks[tpos++] = sole | ((unsigned int)(base + j) << 12) | (unsigned int)k;
        }
    }
    if (t == 255) {
        offsets[NB2] = run;
        task_count[0] = tbase_s[255];
    }
}

// Compact kept points: block-aggregated reservation (one global atomic per
// block x touched-bucket); cnt[] is reused to hold the global base (25.6 KB).
__global__ void __launch_bounds__(256) place_kernel(
        const unsigned int* __restrict__ pcode,
        int* __restrict__ cursor,
        unsigned int* __restrict__ entries) {
    __shared__ int cnt[NB2];   // 25.6 KB (counts, then global bases)
    int t = threadIdx.x;
    int p = blockIdx.x * 256 + t;
    for (int i = t; i < NB2; i += 256) cnt[i] = 0;
    __syncthreads();
    unsigned int code = pcode[p];
    bool kept = (code != 0xFFFFFFFFu);
    int bk = (int)(code >> 6);
    int lr = 0;
    if (kept) lr = atomicAdd(&cnt[bk], 1);
    __syncthreads();
    for (int i = t; i < NB2; i += 256) {
        int c = cnt[i];
        if (c) cnt[i] = atomicAdd(&cursor[i], c);   // overwrite with global base
    }
    __syncthreads();
    if (kept)
        entries[cnt[bk] + lr] = ((code & 63u) << 19) | (unsigned int)p;
}

// Static grid-stride gather over size-capped tasks (CAP=128): one block,
// 8 waves, ILP-8 -> accumulate chain of ~2 latency groups per task.
// Out is pre-zeroed: sole tasks store nonzero cells, multi-chunk tasks
// atomic-flush, tiny tasks (n<=DIRECT_N) bypass LDS with direct atomics.
#define LDS_STRIDE 51
__global__ void __launch_bounds__(512) gather_kernel(
        const float* __restrict__ x_feats,
        const unsigned int* __restrict__ entries,
        const int* __restrict__ offsets,
        const unsigned int* __restrict__ tasks,
        const int* __restrict__ task_count,
        float* __restrict__ out) {
    __shared__ float acc[C_ * LDS_STRIDE]; // 13056 B
    int ntask = task_count[0];
    int t = threadIdx.x, wave = t >> 6, lane = t & 63;

    for (int tid = blockIdx.x; tid < ntask; tid += GATHER_BLOCKS) {
        unsigned int task = tasks[tid];
        int sole = (int)(task >> 31);
        int bk   = (int)((task >> 12) & 0x1FFFu);
        int ch   = (int)(task & 0xFFFu);
        int s = offsets[bk] + ch * CAP;
        int e = offsets[bk + 1];
        if (e > s + CAP) e = s + CAP;
        int n = e - s;

        int b   = bk / (NX0 * G1Q);
        int rem = bk % (NX0 * G1Q);
        int g0  = rem / G1Q, g1q = rem % G1Q;
        size_t obase = (size_t)b * (C_ * NX0 * NX1) + (size_t)g0 * NX1 + g1q * 50;

        if (n <= DIRECT_N) {
            for (int i = wave; i < n; i += 8) {
                unsigned int v = entries[s + i];
                float f = x_feats[(size_t)(v & 0x7FFFFu) * C_ + lane];
                unsafeAtomicAdd(&out[obase + (size_t)lane * (NX0 * NX1) + (int)(v >> 19)], f);
            }
            continue;
        }

        for (int i = t; i < C_ * LDS_STRIDE; i += 512) acc[i] = 0.0f;
        __syncthreads();

        // full 64-entry sweeps: 8 waves x 8-entry ILP
        int nfull = (n >> 6) << 6;
        for (int sbase = 0; sbase < nfull; sbase += 64) {
            int i0 = s + sbase + wave * 8;
            unsigned int v0 = entries[i0],     v1 = entries[i0 + 1];
            unsigned int v2 = entries[i0 + 2], v3 = entries[i0 + 3];
            unsigned int v4 = entries[i0 + 4], v5 = entries[i0 + 5];
            unsigned int v6 = entries[i0 + 6], v7 = entries[i0 + 7];
            float f0 = x_feats[(size_t)(v0 & 0x7FFFFu) * C_ + lane];
            float f1 = x_feats[(size_t)(v1 & 0x7FFFFu) * C_ + lane];
            float f2 = x_feats[(size_t)(v2 & 0x7FFFFu) * C_ + lane];
            float f3 = x_feats[(size_t)(v3 & 0x7FFFFu) * C_ + lane];
            float f4 = x_feats[(size_t)(v4 & 0x7FFFFu) * C_ + lane];
            float f5 = x_feats[(size_t)(v5 & 0x7FFFFu) * C_ + lane];
            float f6 = x_feats[(size_t)(v6 & 0x7FFFFu) * C_ + lane];
            float f7 = x_feats[(size_t)(v7 & 0x7FFFFu) * C_ + lane];
            int lb = lane * LDS_STRIDE;
            atomicAdd(&acc[lb + (int)(v0 >> 19)], f0);
            atomicAdd(&acc[lb + (int)(v1 >> 19)], f1);
            atomicAdd(&acc[lb + (int)(v2 >> 19)], f2);
            atomicAdd(&acc[lb + (int)(v3 >> 19)], f3);
            atomicAdd(&acc[lb + (int)(v4 >> 19)], f4);
            atomicAdd(&acc[lb + (int)(v5 >> 19)], f5);
            atomicAdd(&acc[lb + (int)(v6 >> 19)], f6);
            atomicAdd(&acc[lb + (int)(v7 >> 19)], f7);
        }
        // tail (< 64 entries): one entry per wave per iteration
        for (int i = nfull + wave; i < n; i += 8) {
            unsigned int v = entries[s + i];
            float f = x_feats[(size_t)(v & 0x7FFFFu) * C_ + lane];
            atomicAdd(&acc[lane * LDS_STRIDE + (int)(v >> 19)], f);
        }
        __syncthreads();

        for (int k = t; k < C_ * 50; k += 512) {
            int c = k / 50, r = k - c * 50;
            float val = acc[c * LDS_STRIDE + r];
            if (val != 0.0f) {
                float* dst = &out[obase + (size_t)c * (NX0 * NX1) + r];
                if (sole) *dst = val;
                else unsafeAtomicAdd(dst, val);
            }
        }
        __syncthreads();   // protect acc before next task's init
    }
}

extern "C" void kernel_launch(void* const* d_in, const int* in_sizes, int n_in,
                              void* d_out, int out_size, void* d_ws, size_t ws_size,
                              hipStream_t stream) {
    const float* x_feats    = (const float*)d_in[0];
    const float* rots       = (const float*)d_in[1];
    const float* trans      = (const float*)d_in[2];
    const float* intrins    = (const float*)d_in[3];
    const float* post_rots  = (const float*)d_in[4];
    const float* post_trans = (const float*)d_in[5];
    float* out = (float*)d_out;

    // ws layout (~3 MB)
    char* w = (char*)d_ws;
    float*        mats       = (float*)w;         w += 48 * 24 * sizeof(float);
    int*          counts     = (int*)w;           w += NB2 * sizeof(int);
    int*          offsets    = (int*)w;           w += (NB2 + 1) * sizeof(int);
    int*          cursor     = (int*)w;           w += NB2 * sizeof(int);
    int*          task_count = (int*)w;           w += 4 * sizeof(int);
    unsigned int* tasks      = (unsigned int*)w;  w += MAXTASKS * sizeof(unsigned int);
    unsigned int* pcode      = (unsigned int*)w;  w += NPRIME * sizeof(unsigned int);
    unsigned int* entries    = (unsigned int*)w;  w += NPRIME * sizeof(unsigned int);

    prep_kernel<<<1, 256, 0, stream>>>(rots, trans, intrins, post_rots, post_trans,
                                       mats, counts);
    geom_kernel<<<NBLK_PTS, 256, 0, stream>>>(mats, pcode, counts, (float4*)out);
    scan_kernel<<<1, 256, 0, stream>>>(counts, offsets, cursor, tasks, task_count);
    place_kernel<<<NBLK_PTS, 256, 0, stream>>>(pcode, cursor, entries);
    gather_kernel<<<GATHER_BLOCKS, 512, 0, stream>>>(x_feats, entries, offsets,
                                                     tasks, task_count, out);
}